// Round 7
// baseline (49.009 us; speedup 1.0000x reference)
//
#include <hip/hip_runtime.h>
#include <math.h>

#define NQ      100
#define BS      8
#define NC      4
#define NPTS    30
#define NTGT    512
#define P_TOTAL (NQ*BS)     /* 800 */
#define TILE_P  8           /* preds per block = waves per block */
#define TILE_T  64          /* tgts per block = lanes per wave */
#define NTHREADS 512

typedef float        f32x2 __attribute__((ext_vector_type(2)));
typedef unsigned int u32x2 __attribute__((ext_vector_type(2)));

// (pred.s - tgt.s, pred.r - tgt.r) with pred pair in SGPRs: ONE v_pk_add_f32
__device__ __forceinline__ f32x2 pksub_sv(u32x2 sp, f32x2 t) {
    f32x2 r;
    asm("v_pk_add_f32 %0, %1, %2 neg_lo:[0,1] neg_hi:[0,1]"
        : "=v"(r) : "s"(sp), "v"(t));
    return r;
}
// Chebyshev of rotated deltas == L1 of original: max(|ds|,|dr|)
__device__ __forceinline__ float maxabs2(f32x2 w) {
    float d;
    asm("v_max_f32 %0, abs(%1), abs(%2)" : "=v"(d) : "v"(w.x), "v"(w.y));
    return d;
}
__device__ __forceinline__ float min3f(float a, float b, float c) {
    float r;
    asm("v_min3_f32 %0, %1, %2, %3" : "=v"(r) : "v"(a), "v"(b), "v"(c));
    return r;
}

__global__ __launch_bounds__(NTHREADS) void matcher_kernel(
    const float* __restrict__ logits,      // [800,4]
    const float* __restrict__ pred_poly,   // [800,30,2]
    const int*   __restrict__ tgt_ids,     // [512]
    const float* __restrict__ tgt_poly,    // [512,30,2]
    float*       __restrict__ out)         // [800,512]
{
    // rotated tgt tile: s = x+y, r = x-y ; [j][t] padded, lane-stride-1 reads
    __shared__ f32x2 srt_t[NPTS][TILE_T + 1];
    __shared__ float prob_lds[TILE_P][NC];

    const int tid = threadIdx.x;
    const int p0  = blockIdx.x * TILE_P;
    const int t0  = blockIdx.y * TILE_T;

    // ---- stage 64 tgt polylines, rotate into (s,r) ----
    for (int idx = tid; idx < TILE_T * NPTS; idx += NTHREADS) {
        const int tt = idx / NPTS;
        const int j  = idx - tt * NPTS;
        const float2 v = *reinterpret_cast<const float2*>(
            tgt_poly + (size_t)(t0 + tt) * (NPTS * 2) + j * 2);
        srt_t[j][tt] = f32x2{v.x + v.y, v.x - v.y};
    }
    // ---- softmax over 4 classes ----
    if (tid < TILE_P) {
        const float* l = logits + (size_t)(p0 + tid) * NC;
        const float a0 = l[0], a1 = l[1], a2 = l[2], a3 = l[3];
        const float m  = fmaxf(fmaxf(a0, a1), fmaxf(a2, a3));
        const float e0 = expf(a0 - m), e1 = expf(a1 - m);
        const float e2 = expf(a2 - m), e3 = expf(a3 - m);
        const float inv = 1.0f / (e0 + e1 + e2 + e3);
        prob_lds[tid][0] = e0 * inv;
        prob_lds[tid][1] = e1 * inv;
        prob_lds[tid][2] = e2 * inv;
        prob_lds[tid][3] = e3 * inv;
    }

    const int w  = tid >> 6;   // pred within tile (wave-uniform)
    const int tl = tid & 63;   // tgt within tile = lane

    // ---- pred polyline -> SGPRs: uniform loads, VALU rotate, readfirstlane.
    // SGPR file is separate from VGPRs: zero occupancy cost, and the defs
    // can't be rematerialized (their VALU sources die here). 60 SGPRs.
    u32x2 sp[NPTS];
    {
        const float2* pp = reinterpret_cast<const float2*>(
            pred_poly + (size_t)(p0 + w) * (NPTS * 2));
#pragma unroll
        for (int i = 0; i < NPTS; ++i) {
            const float2 v = pp[i];   // same addr across wave -> one fetch
            sp[i].x = __builtin_amdgcn_readfirstlane(__float_as_uint(v.x + v.y));
            sp[i].y = __builtin_amdgcn_readfirstlane(__float_as_uint(v.x - v.y));
        }
    }
    __syncthreads();

    // loop-carried accumulators: min over j for each pred point i.
    // NOT rematerializable -> must stay resident (the R1-R5 disease is gone
    // by construction: there is no loop-invariant register array anymore).
    float m1[NPTS];
#pragma unroll
    for (int i = 0; i < NPTS; ++i) m1[i] = 1e30f;

    float sum2 = 0.0f;
#pragma unroll 1
    for (int j2 = 0; j2 < NPTS / 2; ++j2) {   // 15 iters, 2 tgt points each
        const f32x2 tv0 = srt_t[2 * j2][tl];      // ds_read_b64, 2-way = free
        const f32x2 tv1 = srt_t[2 * j2 + 1][tl];
        float dj0 = 1e30f, dj1 = 1e30f;
#pragma unroll
        for (int i = 0; i < NPTS; i += 2) {
            const float d00 = maxabs2(pksub_sv(sp[i],     tv0));
            const float d01 = maxabs2(pksub_sv(sp[i],     tv1));
            const float d10 = maxabs2(pksub_sv(sp[i + 1], tv0));
            const float d11 = maxabs2(pksub_sv(sp[i + 1], tv1));
            m1[i]     = min3f(m1[i],     d00, d01);
            m1[i + 1] = min3f(m1[i + 1], d10, d11);
            dj0       = min3f(dj0, d00, d10);
            dj1       = min3f(dj1, d01, d11);
        }
        sum2 += dj0 + dj1;   // min over i for tgt points 2j2, 2j2+1
    }

    float sum1 = 0.0f;
#pragma unroll
    for (int i = 0; i < NPTS; ++i) sum1 += m1[i];

    const int   t   = t0 + tl;
    const int   cls = tgt_ids[t];
    const float cc  = -prob_lds[w][cls];
    out[(size_t)(p0 + w) * NTGT + t] = cc + (sum1 + sum2) * (0.5f / (float)NPTS);
}

extern "C" void kernel_launch(void* const* d_in, const int* in_sizes, int n_in,
                              void* d_out, int out_size, void* d_ws, size_t ws_size,
                              hipStream_t stream) {
    const float* logits    = (const float*)d_in[0];
    const float* pred_poly = (const float*)d_in[1];
    const int*   tids      = (const int*)d_in[2];
    const float* tgt_poly  = (const float*)d_in[3];
    float*       out       = (float*)d_out;

    dim3 grid(P_TOTAL / TILE_P, NTGT / TILE_T);  // (100, 8)
    dim3 block(NTHREADS);
    matcher_kernel<<<grid, block, 0, stream>>>(logits, pred_poly, tids, tgt_poly, out);
}

// Round 8
// 47.360 us; speedup vs baseline: 1.0348x; 1.0348x over previous
//
#include <hip/hip_runtime.h>
#include <math.h>

#define NQ      100
#define BS      8
#define NC      4
#define NPTS    30
#define JH      15          /* tgt points owned per lane of a pair */
#define NTGT    512
#define P_TOTAL (NQ*BS)     /* 800 */
#define TILE_P  4           /* preds per block = waves per block */
#define TILE_T  32          /* tgts per block; lane pairs share one tgt */
#define NTHREADS 256

typedef float        f32x2 __attribute__((ext_vector_type(2)));
typedef unsigned int u32x2 __attribute__((ext_vector_type(2)));

// (pred.s - tgt.s, pred.r - tgt.r), pred pair in SGPRs: ONE v_pk_add_f32
__device__ __forceinline__ f32x2 pksub_sv(u32x2 sp, f32x2 t) {
    f32x2 r;
    asm("v_pk_add_f32 %0, %1, %2 neg_lo:[0,1] neg_hi:[0,1]"
        : "=v"(r) : "s"(sp), "v"(t));
    return r;
}
// Chebyshev of rotated deltas == L1 of original: max(|ds|,|dr|)
__device__ __forceinline__ float maxabs2(f32x2 w) {
    float d;
    asm("v_max_f32 %0, abs(%1), abs(%2)" : "=v"(d) : "v"(w.x), "v"(w.y));
    return d;
}
__device__ __forceinline__ float min3f(float a, float b, float c) {
    float r;
    asm("v_min3_f32 %0, %1, %2, %3" : "=v"(r) : "v"(a), "v"(b), "v"(c));
    return r;
}

__global__ __launch_bounds__(NTHREADS) void matcher_kernel(
    const float* __restrict__ logits,      // [800,4]
    const float* __restrict__ pred_poly,   // [800,30,2]
    const int*   __restrict__ tgt_ids,     // [512]
    const float* __restrict__ tgt_poly,    // [512,30,2]
    float*       __restrict__ out)         // [800,512]
{
    // rotated tgt tile: s = x+y, r = x-y ; [j][t] padded
    __shared__ f32x2 srt[NPTS][TILE_T + 1];
    __shared__ float prob_lds[TILE_P][NC];

    const int tid = threadIdx.x;
    const int p0  = blockIdx.x * TILE_P;
    const int t0  = blockIdx.y * TILE_T;

    // ---- stage 32 tgt polylines, rotate into (s,r) ----
    for (int idx = tid; idx < TILE_T * NPTS; idx += NTHREADS) {
        const int tt = idx / NPTS;
        const int j  = idx - tt * NPTS;
        const float2 v = *reinterpret_cast<const float2*>(
            tgt_poly + (size_t)(t0 + tt) * (NPTS * 2) + j * 2);
        srt[j][tt] = f32x2{v.x + v.y, v.x - v.y};
    }
    // ---- softmax over 4 classes ----
    if (tid < TILE_P) {
        const float* l = logits + (size_t)(p0 + tid) * NC;
        const float a0 = l[0], a1 = l[1], a2 = l[2], a3 = l[3];
        const float m  = fmaxf(fmaxf(a0, a1), fmaxf(a2, a3));
        const float e0 = expf(a0 - m), e1 = expf(a1 - m);
        const float e2 = expf(a2 - m), e3 = expf(a3 - m);
        const float inv = 1.0f / (e0 + e1 + e2 + e3);
        prob_lds[tid][0] = e0 * inv;
        prob_lds[tid][1] = e1 * inv;
        prob_lds[tid][2] = e2 * inv;
        prob_lds[tid][3] = e3 * inv;
    }

    const int w    = tid >> 6;          // pred within tile (wave-uniform)
    const int lane = tid & 63;
    const int t    = lane >> 1;         // tgt within tile, shared by lane pair
    const int jb   = (lane & 1) * JH;   // which 15 tgt points this lane owns

    // ---- pred polyline -> SGPRs (uniform across wave; i-index is uniform
    // so SGPR indexing is legal — unlike R5's lane-varying split) ----
    u32x2 sp[NPTS];
    {
        const float2* pp = reinterpret_cast<const float2*>(
            pred_poly + (size_t)(p0 + w) * (NPTS * 2));
#pragma unroll
        for (int i = 0; i < NPTS; ++i) {
            const float2 v = pp[i];
            sp[i].x = __builtin_amdgcn_readfirstlane(__float_as_uint(v.x + v.y));
            sp[i].y = __builtin_amdgcn_readfirstlane(__float_as_uint(v.x - v.y));
        }
    }
    __syncthreads();

    // m1[i] = min over THIS LANE'S j-half; loop-carried accumulators
    // (remat-proof by construction — R6 lesson, now with 2x the waves).
    float m1[NPTS];
#pragma unroll
    for (int i = 0; i < NPTS; ++i) m1[i] = 1e30f;

    float sum2 = 0.0f;
#pragma unroll 1
    for (int jp = 0; jp < JH / 2; ++jp) {     // 7 iters, 2 own tgt points each
        const f32x2 tv0 = srt[jb + 2 * jp][t];
        const f32x2 tv1 = srt[jb + 2 * jp + 1][t];
        float dj0 = 1e30f, dj1 = 1e30f;
#pragma unroll
        for (int i = 0; i < NPTS; i += 2) {
            const float d00 = maxabs2(pksub_sv(sp[i],     tv0));
            const float d01 = maxabs2(pksub_sv(sp[i],     tv1));
            const float d10 = maxabs2(pksub_sv(sp[i + 1], tv0));
            const float d11 = maxabs2(pksub_sv(sp[i + 1], tv1));
            m1[i]     = min3f(m1[i],     d00, d01);
            m1[i + 1] = min3f(m1[i + 1], d10, d11);
            dj0       = min3f(dj0, d00, d10);
            dj1       = min3f(dj1, d01, d11);
        }
        sum2 += dj0 + dj1;
    }
    {   // tail: own tgt point jb+14
        const f32x2 tv0 = srt[jb + JH - 1][t];
        float dj0 = 1e30f;
#pragma unroll
        for (int i = 0; i < NPTS; i += 2) {
            const float d00 = maxabs2(pksub_sv(sp[i],     tv0));
            const float d10 = maxabs2(pksub_sv(sp[i + 1], tv0));
            m1[i]     = fminf(m1[i],     d00);
            m1[i + 1] = fminf(m1[i + 1], d10);
            dj0       = min3f(dj0, d00, d10);
        }
        sum2 += dj0;
    }

    // combine lane pair: sum2 over both j-halves; m1 = min across halves
    sum2 += __shfl_xor(sum2, 1, 64);
    float sum1 = 0.0f;
#pragma unroll
    for (int i = 0; i < NPTS; ++i) {
        const float o = __shfl_xor(m1[i], 1, 64);
        sum1 += fminf(m1[i], o);
    }

    if ((lane & 1) == 0) {
        const int   tg  = t0 + t;
        const int   cls = tgt_ids[tg];
        const float cc  = -prob_lds[w][cls];
        out[(size_t)(p0 + w) * NTGT + tg] = cc + (sum1 + sum2) * (0.5f / (float)NPTS);
    }
}

extern "C" void kernel_launch(void* const* d_in, const int* in_sizes, int n_in,
                              void* d_out, int out_size, void* d_ws, size_t ws_size,
                              hipStream_t stream) {
    const float* logits    = (const float*)d_in[0];
    const float* pred_poly = (const float*)d_in[1];
    const int*   tids      = (const int*)d_in[2];
    const float* tgt_poly  = (const float*)d_in[3];
    float*       out       = (float*)d_out;

    dim3 grid(P_TOTAL / TILE_P, NTGT / TILE_T);  // (200, 16)
    dim3 block(NTHREADS);
    matcher_kernel<<<grid, block, 0, stream>>>(logits, pred_poly, tids, tgt_poly, out);
}

// Round 9
// 46.553 us; speedup vs baseline: 1.0528x; 1.0173x over previous
//
#include <hip/hip_runtime.h>
#include <math.h>

#define NQ      100
#define BS      8
#define NC      4
#define NPTS    30
#define NTGT    512
#define P_TOTAL (NQ*BS)     /* 800 */
#define TILE_P  4           /* preds per block = waves per block */
#define TILE_T  64          /* tgts per block = lanes per wave */
#define NTHREADS 256

typedef float f32x2 __attribute__((ext_vector_type(2)));

// (pred.s - tgt.s, pred.r - tgt.r): ONE v_pk_add_f32, all-VGPR operands
// (R6 evidence: the SGPR-pair operand variant cost ~+5us in the hot loop).
__device__ __forceinline__ f32x2 pksub(f32x2 p, f32x2 t) {
    f32x2 r;
    asm("v_pk_add_f32 %0, %1, %2 neg_lo:[0,1] neg_hi:[0,1]"
        : "=v"(r) : "v"(p), "v"(t));
    return r;
}
// Chebyshev of rotated deltas == L1 of original: max(|ds|,|dr|)
__device__ __forceinline__ float maxabs2(f32x2 w) {
    float d;
    asm("v_max_f32 %0, abs(%1), abs(%2)" : "=v"(d) : "v"(w.x), "v"(w.y));
    return d;
}
__device__ __forceinline__ float min3f(float a, float b, float c) {
    float r;
    asm("v_min3_f32 %0, %1, %2, %3" : "=v"(r) : "v"(a), "v"(b), "v"(c));
    return r;
}

__global__ __launch_bounds__(NTHREADS) void matcher_kernel(
    const float* __restrict__ logits,      // [800,4]
    const float* __restrict__ pred_poly,   // [800,30,2]
    const int*   __restrict__ tgt_ids,     // [512]
    const float* __restrict__ tgt_poly,    // [512,30,2]
    float*       __restrict__ out)         // [800,512]
{
    // rotated coords: s = x+y, r = x-y
    __shared__ f32x2 srt_t[NPTS][TILE_T + 1];  // [j][t] padded; lane-varying reads
    __shared__ f32x2 srt_p[TILE_P][NPTS];      // wave-uniform broadcast reads
    __shared__ float prob_lds[TILE_P][NC];

    const int tid = threadIdx.x;
    const int p0  = blockIdx.x * TILE_P;
    const int t0  = blockIdx.y * TILE_T;

    // ---- stage 64 tgt polylines, rotate into (s,r) ----
    for (int idx = tid; idx < TILE_T * NPTS; idx += NTHREADS) {
        const int tt = idx / NPTS;
        const int j  = idx - tt * NPTS;
        const float2 v = *reinterpret_cast<const float2*>(
            tgt_poly + (size_t)(t0 + tt) * (NPTS * 2) + j * 2);
        srt_t[j][tt] = f32x2{v.x + v.y, v.x - v.y};
    }
    // ---- stage 4 pred polylines, rotate ----
    if (tid < TILE_P * NPTS) {
        const int pp = tid / NPTS;
        const int i  = tid - pp * NPTS;
        const float2 v = *reinterpret_cast<const float2*>(
            pred_poly + (size_t)(p0 + pp) * (NPTS * 2) + i * 2);
        srt_p[pp][i] = f32x2{v.x + v.y, v.x - v.y};
    }
    // ---- softmax over 4 classes ----
    if (tid < TILE_P) {
        const float* l = logits + (size_t)(p0 + tid) * NC;
        const float a0 = l[0], a1 = l[1], a2 = l[2], a3 = l[3];
        const float m  = fmaxf(fmaxf(a0, a1), fmaxf(a2, a3));
        const float e0 = expf(a0 - m), e1 = expf(a1 - m);
        const float e2 = expf(a2 - m), e3 = expf(a3 - m);
        const float inv = 1.0f / (e0 + e1 + e2 + e3);
        prob_lds[tid][0] = e0 * inv;
        prob_lds[tid][1] = e1 * inv;
        prob_lds[tid][2] = e2 * inv;
        prob_lds[tid][3] = e3 * inv;
    }
    __syncthreads();

    const int w    = tid >> 6;   // pred within tile (wave-uniform)
    const int lane = tid & 63;   // tgt within tile = lane

    // m1[i] = min over j; loop-carried accumulators (remat-proof, R6 lesson).
    float m1[NPTS];
#pragma unroll
    for (int i = 0; i < NPTS; ++i) m1[i] = 1e30f;

    float sum2 = 0.0f;
    // outer: MY two tgt points (lane-varying, 4 VGPRs live across inner —
    // too small to trigger remat); inner: stream pred points as broadcast
    // ds_read_b64 with immediate offsets (conflict-free, no SGPR hazard).
#pragma unroll 1
    for (int jp = 0; jp < NPTS / 2; ++jp) {
        const f32x2 tv0 = srt_t[2 * jp][lane];
        const f32x2 tv1 = srt_t[2 * jp + 1][lane];
        float dj0 = 1e30f, dj1 = 1e30f;
#pragma unroll
        for (int i = 0; i < NPTS; i += 2) {
            const f32x2 sp0 = srt_p[w][i];       // broadcast (uniform addr)
            const f32x2 sp1 = srt_p[w][i + 1];
            const float d00 = maxabs2(pksub(sp0, tv0));
            const float d01 = maxabs2(pksub(sp0, tv1));
            const float d10 = maxabs2(pksub(sp1, tv0));
            const float d11 = maxabs2(pksub(sp1, tv1));
            m1[i]     = min3f(m1[i],     d00, d01);   // min over j for point i
            m1[i + 1] = min3f(m1[i + 1], d10, d11);
            dj0       = min3f(dj0, d00, d10);          // min over i for j0
            dj1       = min3f(dj1, d01, d11);          // min over i for j1
        }
        sum2 += dj0 + dj1;
    }

    float sum1 = 0.0f;
#pragma unroll
    for (int i = 0; i < NPTS; ++i) sum1 += m1[i];

    const int   t   = t0 + lane;
    const int   cls = tgt_ids[t];
    const float cc  = -prob_lds[w][cls];
    out[(size_t)(p0 + w) * NTGT + t] = cc + (sum1 + sum2) * (0.5f / (float)NPTS);
}

extern "C" void kernel_launch(void* const* d_in, const int* in_sizes, int n_in,
                              void* d_out, int out_size, void* d_ws, size_t ws_size,
                              hipStream_t stream) {
    const float* logits    = (const float*)d_in[0];
    const float* pred_poly = (const float*)d_in[1];
    const int*   tids      = (const int*)d_in[2];
    const float* tgt_poly  = (const float*)d_in[3];
    float*       out       = (float*)d_out;

    dim3 grid(P_TOTAL / TILE_P, NTGT / TILE_T);  // (200, 8) = 1600 blocks
    dim3 block(NTHREADS);
    matcher_kernel<<<grid, block, 0, stream>>>(logits, pred_poly, tids, tgt_poly, out);
}

// Round 10
// 41.983 us; speedup vs baseline: 1.1673x; 1.1088x over previous
//
#include <hip/hip_runtime.h>
#include <math.h>

#define NQ      100
#define BS      8
#define NC      4
#define NPTS    30
#define NJP     (NPTS/2)    /* 15 point-pairs */
#define NTGT    512
#define P_TOTAL (NQ*BS)     /* 800 */
#define TILE_P  4           /* preds per block = waves per block */
#define TILE_T  64          /* tgts per block = lanes per wave */
#define NTHREADS 256

// NO inline asm anywhere: R1-R8 evidence says compiler codegen (abs modifiers,
// v_min3 fusion, free scheduling) beats constrained asm blocks by ~15-25%.

__global__ __launch_bounds__(NTHREADS) void matcher_kernel(
    const float* __restrict__ logits,      // [800,4]
    const float* __restrict__ pred_poly,   // [800,30,2]
    const int*   __restrict__ tgt_ids,     // [512]
    const float* __restrict__ tgt_poly,    // [512,30,2]
    float*       __restrict__ out)         // [800,512]
{
    // rotated coords s=x+y, r=x-y; POINT-PAIR packed float4 (s0,r0,s1,r1):
    // tgt tile read as ONE ds_read_b128 per 2 points (lane-contiguous 16B =>
    // full-bandwidth, no pathological conflict); pred tile broadcast b128.
    __shared__ float4 srt_t[NJP][TILE_T];   // [jp][t]
    __shared__ float4 srt_p[TILE_P][NJP];   // [p][ip]
    __shared__ float  prob_lds[TILE_P][NC];

    const int tid = threadIdx.x;
    const int p0  = blockIdx.x * TILE_P;
    const int t0  = blockIdx.y * TILE_T;

    // ---- stage 64 tgt polylines: global float4 = 2 points, rotate, store ----
    for (int idx = tid; idx < TILE_T * NJP; idx += NTHREADS) {
        const int tt = idx / NJP;        // tgt within tile
        const int jp = idx - tt * NJP;   // point pair
        const float4 v = *reinterpret_cast<const float4*>(
            tgt_poly + (size_t)(t0 + tt) * (NPTS * 2) + jp * 4);
        srt_t[jp][tt] = make_float4(v.x + v.y, v.x - v.y, v.z + v.w, v.z - v.w);
    }
    // ---- stage 4 pred polylines, same packing ----
    if (tid < TILE_P * NJP) {
        const int pp = tid / NJP;
        const int ip = tid - pp * NJP;
        const float4 v = *reinterpret_cast<const float4*>(
            pred_poly + (size_t)(p0 + pp) * (NPTS * 2) + ip * 4);
        srt_p[pp][ip] = make_float4(v.x + v.y, v.x - v.y, v.z + v.w, v.z - v.w);
    }
    // ---- softmax over 4 classes ----
    if (tid < TILE_P) {
        const float* l = logits + (size_t)(p0 + tid) * NC;
        const float a0 = l[0], a1 = l[1], a2 = l[2], a3 = l[3];
        const float m  = fmaxf(fmaxf(a0, a1), fmaxf(a2, a3));
        const float e0 = expf(a0 - m), e1 = expf(a1 - m);
        const float e2 = expf(a2 - m), e3 = expf(a3 - m);
        const float inv = 1.0f / (e0 + e1 + e2 + e3);
        prob_lds[tid][0] = e0 * inv;
        prob_lds[tid][1] = e1 * inv;
        prob_lds[tid][2] = e2 * inv;
        prob_lds[tid][3] = e3 * inv;
    }
    __syncthreads();

    const int w    = tid >> 6;   // pred within tile (wave-uniform)
    const int lane = tid & 63;   // tgt within tile = lane

    // m1[i] = min over j for pred point i: loop-carried scalars (remat-proof).
    float m1[NPTS];
#pragma unroll
    for (int i = 0; i < NPTS; ++i) m1[i] = 1e30f;

    float sum2 = 0.0f;
    // outer: my 2 tgt points (one b128, lane-varying); inner: 2 pred points
    // per iter (one broadcast b128). Plain-C 2x2 core: compiler emits
    // v_sub x2 + v_max abs,abs + v_min3 per pair = 4 instr/pair.
#pragma unroll 1
    for (int jp = 0; jp < NJP; ++jp) {
        const float4 tq = srt_t[jp][lane];   // (ts0, tr0, ts1, tr1)
        float dj0 = 1e30f, dj1 = 1e30f;
#pragma unroll
        for (int ip = 0; ip < NJP; ++ip) {
            const float4 pq = srt_p[w][ip];  // (ps0, pr0, ps1, pr1) broadcast
            const float d00 = fmaxf(fabsf(pq.x - tq.x), fabsf(pq.y - tq.y));
            const float d01 = fmaxf(fabsf(pq.x - tq.z), fabsf(pq.y - tq.w));
            const float d10 = fmaxf(fabsf(pq.z - tq.x), fabsf(pq.w - tq.y));
            const float d11 = fmaxf(fabsf(pq.z - tq.z), fabsf(pq.w - tq.w));
            m1[2 * ip]     = fminf(fminf(m1[2 * ip],     d00), d01); // v_min3
            m1[2 * ip + 1] = fminf(fminf(m1[2 * ip + 1], d10), d11);
            dj0            = fminf(fminf(dj0, d00), d10);
            dj1            = fminf(fminf(dj1, d01), d11);
        }
        sum2 += dj0 + dj1;
    }

    float sum1 = 0.0f;
#pragma unroll
    for (int i = 0; i < NPTS; ++i) sum1 += m1[i];

    const int   t   = t0 + lane;
    const int   cls = tgt_ids[t];
    const float cc  = -prob_lds[w][cls];
    out[(size_t)(p0 + w) * NTGT + t] = cc + (sum1 + sum2) * (0.5f / (float)NPTS);
}

extern "C" void kernel_launch(void* const* d_in, const int* in_sizes, int n_in,
                              void* d_out, int out_size, void* d_ws, size_t ws_size,
                              hipStream_t stream) {
    const float* logits    = (const float*)d_in[0];
    const float* pred_poly = (const float*)d_in[1];
    const int*   tids      = (const int*)d_in[2];
    const float* tgt_poly  = (const float*)d_in[3];
    float*       out       = (float*)d_out;

    dim3 grid(P_TOTAL / TILE_P, NTGT / TILE_T);  // (200, 8) = 1600 blocks
    dim3 block(NTHREADS);
    matcher_kernel<<<grid, block, 0, stream>>>(logits, pred_poly, tids, tgt_poly, out);
}